// Round 12
// baseline (178.736 us; speedup 1.0000x reference)
//
#include <hip/hip_runtime.h>

#define D 128          // D_IN == D_OUT == 128
#define RPB 256        // rows per bucket == rows per csr_build block
#define RPB_SHIFT 8
#define BUCKMAX 512
#define TILE 8192      // edges per binning tile
#define SEGCAP 7168    // LDS pair capacity per csr_build block (56 KiB)

typedef short bf16x8 __attribute__((ext_vector_type(8)));
typedef float f32x4 __attribute__((ext_vector_type(4)));

__device__ inline unsigned short f2bf(float f) {  // RNE float->bf16
    unsigned u = __float_as_uint(f);
    unsigned r = u + 0x7FFFu + ((u >> 16) & 1u);
    return (unsigned short)(r >> 16);
}

// ---------------------------------------------------------------------------
// Phase A: cast x fp32->bf16 (grid-stride; block 0 zeros bucketCnt first via
// a separate early loop -- harness memset dispatch eliminated).
// Phase B: per-bucket edge histogram (grid-stride over E), LDS-accumulated.
// ---------------------------------------------------------------------------
__global__ __launch_bounds__(256) void cast_x_hist(const float* __restrict__ x,
                                                   unsigned short* __restrict__ xb,
                                                   long long n4,
                                                   const int* __restrict__ rows,
                                                   int* __restrict__ bucketCnt,
                                                   int E, int NBUCK) {
    if (blockIdx.x == 0) {
        bucketCnt[threadIdx.x] = 0;
        bucketCnt[threadIdx.x + 256] = 0;
    }
    {
        long long i = (long long)blockIdx.x * 256 + threadIdx.x;
        const long long stride = (long long)gridDim.x * 256;
        for (; i < n4; i += stride) {
            float4 v = reinterpret_cast<const float4*>(x)[i];
            ushort4 o;
            o.x = f2bf(v.x); o.y = f2bf(v.y); o.z = f2bf(v.z); o.w = f2bf(v.w);
            reinterpret_cast<ushort4*>(xb)[i] = o;
        }
    }
    __shared__ int h[BUCKMAX];
    for (int i = threadIdx.x; i < BUCKMAX; i += 256) h[i] = 0;
    __syncthreads();
    {
        long long i = (long long)blockIdx.x * 256 + threadIdx.x;
        const long long stride = (long long)gridDim.x * 256;
        for (; i < E; i += stride) atomicAdd(&h[rows[i] >> RPB_SHIFT], 1);
    }
    __syncthreads();
    for (int i = threadIdx.x; i < NBUCK; i += 256)
        if (h[i]) atomicAdd(&bucketCnt[i], h[i]);  // device-scope (cross-block)
}

// ---------------------------------------------------------------------------
// Block 0: exclusive scan over NBUCK (<=512) bucket counts (2/thread);
//          zero cursors. Block 1: cast W -> bf16.
// ---------------------------------------------------------------------------
__global__ __launch_bounds__(256) void scan_castW(const int* __restrict__ bucketCnt,
                                                  int* __restrict__ bucketBase,
                                                  int* __restrict__ bucketCur,
                                                  int* __restrict__ offsets,
                                                  int NBUCK, int N,
                                                  const float* __restrict__ W,
                                                  unsigned short* __restrict__ Wb) {
    const int tid = threadIdx.x;
    if (blockIdx.x == 1) {  // cast W (128x128 fp32 -> bf16)
        for (int idx = tid; idx < D * D / 4; idx += 256) {
            float4 v = reinterpret_cast<const float4*>(W)[idx];
            ushort4 o;
            o.x = f2bf(v.x); o.y = f2bf(v.y); o.z = f2bf(v.z); o.w = f2bf(v.w);
            reinterpret_cast<ushort4*>(Wb)[idx] = o;
        }
        return;
    }
    __shared__ int t[256];
    const int i0 = tid * 2, i1 = tid * 2 + 1;
    int v0 = (i0 < NBUCK) ? bucketCnt[i0] : 0;
    int v1 = (i1 < NBUCK) ? bucketCnt[i1] : 0;
    int s = v0 + v1;
    t[tid] = s;
    __syncthreads();
    for (int ofs = 1; ofs < 256; ofs <<= 1) {
        int add = (tid >= ofs) ? t[tid - ofs] : 0;
        __syncthreads();
        t[tid] += add;
        __syncthreads();
    }
    const int base0 = t[tid] - s;  // exclusive base for i0
    if (i0 < NBUCK) { bucketBase[i0] = base0;      bucketCur[i0] = 0; }
    if (i1 < NBUCK) { bucketBase[i1] = base0 + v0; bucketCur[i1] = 0; }
    if (tid == 255) {
        bucketBase[NBUCK] = t[255];
        offsets[N] = t[255];  // == E
    }
}

// ---------------------------------------------------------------------------
// Pass 1: bin edges into bucket-major PACKED pairs: (lrow8<<23 | col, val).
// Row ids kept in registers across phases (8/thread, fully unrolled).
// ---------------------------------------------------------------------------
__global__ __launch_bounds__(1024) void binA(const int* __restrict__ rows,
                                             const int* __restrict__ cols,
                                             const float* __restrict__ vals,
                                             const int* __restrict__ bucketBase,
                                             int* __restrict__ bucketCur,
                                             uint2* __restrict__ pairs_bin,
                                             int E, int NBUCK) {
    __shared__ int h[BUCKMAX];
    __shared__ int base[BUCKMAX];
    const int t0 = blockIdx.x * TILE;
    const int tend = min(t0 + TILE, E);
    for (int i = threadIdx.x; i < BUCKMAX; i += 1024) h[i] = 0;
    __syncthreads();

    int rreg[8];  // TILE/1024 == 8 edges per thread
#pragma unroll
    for (int k = 0; k < 8; ++k) {
        const int i = t0 + threadIdx.x + k * 1024;
        rreg[k] = (i < tend) ? rows[i] : -1;
        if (rreg[k] >= 0) atomicAdd(&h[rreg[k] >> RPB_SHIFT], 1);
    }
    __syncthreads();
    for (int i = threadIdx.x; i < NBUCK; i += 1024) {
        int c = h[i];
        base[i] = c ? bucketBase[i] + atomicAdd(&bucketCur[i], c) : 0;
        h[i] = 0;  // reuse as local cursor
    }
    __syncthreads();
#pragma unroll
    for (int k = 0; k < 8; ++k) {
        const int i = t0 + threadIdx.x + k * 1024;
        if (i < tend) {
            const int r = rreg[k];
            const int b = r >> RPB_SHIFT;
            const int p = base[b] + atomicAdd(&h[b], 1);
            const unsigned pk = ((unsigned)(r & (RPB - 1)) << 23) | (unsigned)cols[i];
            pairs_bin[p] = make_uint2(pk, __float_as_uint(vals[i]));
        }
    }
}

// ---------------------------------------------------------------------------
// Pass 2: ONE block per 256-row bucket (single read of its pair range --
// RPB==block rows, no half-split double-read). Sorted segment built in LDS,
// written out coalesced; per-row offsets emitted. Overflow (>SEGCAP) falls
// back to direct global scatter.
// ---------------------------------------------------------------------------
__global__ __launch_bounds__(256) void csr_build(const uint2* __restrict__ pairs_bin,
                                                 const int* __restrict__ bucketBase,
                                                 int* __restrict__ offsets,
                                                 uint2* __restrict__ pairs_g, int N) {
    __shared__ int hist[RPB];
    __shared__ int cur[RPB];
    __shared__ int tsum[256];
    __shared__ uint2 pr[SEGCAP];
    const int tid = threadIdx.x;
    const int buck = blockIdx.x;
    const int grow0 = buck * RPB;
    const int rbeg = bucketBase[buck], rend = bucketBase[buck + 1];

    hist[tid] = 0;
    __syncthreads();

    for (int i = rbeg + tid; i < rend; i += 256)
        atomicAdd(&hist[pairs_bin[i].x >> 23], 1);
    __syncthreads();

    int part = hist[tid];
    tsum[tid] = part;
    __syncthreads();
    for (int ofs = 1; ofs < 256; ofs <<= 1) {
        int add = (tid >= ofs) ? tsum[tid - ofs] : 0;
        __syncthreads();
        tsum[tid] += add;
        __syncthreads();
    }
    const int excl = tsum[tid] - part;
    const int segcnt = tsum[255];  // == rend - rbeg

    cur[tid] = excl;
    const int grow = grow0 + tid;
    if (grow < N) offsets[grow] = rbeg + excl;
    __syncthreads();

    if (segcnt <= SEGCAP) {
        for (int i = rbeg + tid; i < rend; i += 256) {
            uint2 e = pairs_bin[i];
            int p = atomicAdd(&cur[e.x >> 23], 1);
            pr[p] = make_uint2(e.x & 0x7FFFFFu, e.y);
        }
        __syncthreads();
        for (int p = tid; p < segcnt; p += 256) pairs_g[rbeg + p] = pr[p];
    } else {  // overflow: direct scatter (correct for any data)
        for (int i = rbeg + tid; i < rend; i += 256) {
            uint2 e = pairs_bin[i];
            int p = atomicAdd(&cur[e.x >> 23], 1);
            pairs_g[rbeg + p] = make_uint2(e.x & 0x7FFFFFu, e.y);
        }
    }
}

// ---------------------------------------------------------------------------
// Aggregation: y[row] = sum val * xb[col]  (bf16 gather, fp32 acc, bf16 out)
// One wave per row, shfl-free LDS-staged batches, 4x dwordx4 gathers in
// flight (R10-proven, 55.7 us).
// ---------------------------------------------------------------------------
__global__ __launch_bounds__(256) void csr_gather_bf16(
    const unsigned short* __restrict__ xb,
    const int* __restrict__ offsets,
    const uint2* __restrict__ pairs,
    unsigned short* __restrict__ yb, int N) {
    __shared__ uint2 prl[4][64];  // 2 KiB, wave-private slices
    const int row = blockIdx.x * 4 + (threadIdx.x >> 6);
    if (row >= N) return;
    const int wave = threadIdx.x >> 6;
    const int lane = threadIdx.x & 63;
    const int g    = lane >> 4;      // edge slot within a 4-edge group
    const int c8   = lane & 15;      // which 8-col chunk of the row
    const int beg = offsets[row], end = offsets[row + 1];

    float a[8] = {};
    for (int base = beg; base < end; base += 64) {
        const int rem = min(end - base, 64);  // wave-uniform
        uint2 e = make_uint2(0u, 0u);         // pads: col 0, val 0
        if (lane < rem) e = pairs[base + lane];
        prl[wave][lane] = e;                  // wave-private: lgkmcnt only
        __builtin_amdgcn_wave_barrier();

        for (int j0 = 0; j0 < rem; j0 += 16) {  // wave-uniform trip count
            uint2 pe[4];
            uint4 u[4];
#pragma unroll
            for (int i = 0; i < 4; ++i)
                pe[i] = prl[wave][j0 + 4 * i + g];  // 16-lane broadcast read
#pragma unroll
            for (int i = 0; i < 4; ++i)
                u[i] = *reinterpret_cast<const uint4*>(
                    xb + (size_t)pe[i].x * D + c8 * 8);
#pragma unroll
            for (int i = 0; i < 4; ++i) {
                const float v = __uint_as_float(pe[i].y);
                const unsigned w0 = u[i].x, w1 = u[i].y, w2 = u[i].z, w3 = u[i].w;
                a[0] = fmaf(v, __uint_as_float(w0 << 16), a[0]);
                a[1] = fmaf(v, __uint_as_float(w0 & 0xFFFF0000u), a[1]);
                a[2] = fmaf(v, __uint_as_float(w1 << 16), a[2]);
                a[3] = fmaf(v, __uint_as_float(w1 & 0xFFFF0000u), a[3]);
                a[4] = fmaf(v, __uint_as_float(w2 << 16), a[4]);
                a[5] = fmaf(v, __uint_as_float(w2 & 0xFFFF0000u), a[5]);
                a[6] = fmaf(v, __uint_as_float(w3 << 16), a[6]);
                a[7] = fmaf(v, __uint_as_float(w3 & 0xFFFF0000u), a[7]);
            }
        }
        __builtin_amdgcn_wave_barrier();  // don't overwrite prl while in use
    }

    // combine lane-groups: lanes l, l^16, l^32, l^48 hold same columns
#pragma unroll
    for (int i = 0; i < 8; ++i) {
        a[i] += __shfl_xor(a[i], 16);
        a[i] += __shfl_xor(a[i], 32);
    }
    if (g == 0) {
        uint4 o;
        o.x = (unsigned)f2bf(a[0]) | ((unsigned)f2bf(a[1]) << 16);
        o.y = (unsigned)f2bf(a[2]) | ((unsigned)f2bf(a[3]) << 16);
        o.z = (unsigned)f2bf(a[4]) | ((unsigned)f2bf(a[5]) << 16);
        o.w = (unsigned)f2bf(a[6]) | ((unsigned)f2bf(a[7]) << 16);
        *reinterpret_cast<uint4*>(yb + (size_t)row * D + c8 * 8) = o;
    }
}

// ---------------------------------------------------------------------------
// Projection: out = y * W^T via MFMA bf16 16x16x32 (layouts m89-verified).
// ---------------------------------------------------------------------------
__global__ __launch_bounds__(256) void gemm_mfma(const unsigned short* __restrict__ yb,
                                                 const unsigned short* __restrict__ Wb,
                                                 float* __restrict__ out, int N) {
    const int wid  = threadIdx.x >> 6;
    const int lane = threadIdx.x & 63;
    const int m0   = blockIdx.x * 64 + wid * 16;
    const int r    = lane & 15;
    const int kg   = lane >> 4;  // 0..3
    const int arow = m0 + r;

    f32x4 acc[8] = {};
#pragma unroll
    for (int ks = 0; ks < 4; ++ks) {
        const int k0 = ks * 32 + kg * 8;
        bf16x8 a = {};
        if (arow < N) a = *reinterpret_cast<const bf16x8*>(yb + (size_t)arow * D + k0);
#pragma unroll
        for (int t = 0; t < 8; ++t) {
            bf16x8 b = *reinterpret_cast<const bf16x8*>(Wb + (size_t)(t * 16 + r) * D + k0);
            acc[t] = __builtin_amdgcn_mfma_f32_16x16x32_bf16(a, b, acc[t], 0, 0, 0);
        }
    }
#pragma unroll
    for (int t = 0; t < 8; ++t) {
#pragma unroll
        for (int i = 0; i < 4; ++i) {
            const int row = m0 + kg * 4 + i;
            if (row < N) out[(size_t)row * D + t * 16 + r] = acc[t][i];
        }
    }
}

// ---------------------------------------------------------------------------
// Fallback path (tiny workspace): fp32 VALU GEMM + atomic scatter
// ---------------------------------------------------------------------------
__global__ __launch_bounds__(256) void gemm64(const float* __restrict__ x,
                                              const float* __restrict__ W,
                                              float* __restrict__ h, int N) {
    __shared__ float xs[128][64];
    __shared__ float ws[128][64];
    const int tid = threadIdx.x;
    const int m0 = blockIdx.x * 64;
    const int n0 = blockIdx.y * 64;
    for (int idx = tid; idx < 2048; idx += 256) {
        int q = idx >> 6, m = idx & 63;
        int grow = m0 + m;
        float4 v = make_float4(0.f, 0.f, 0.f, 0.f);
        if (grow < N) v = *reinterpret_cast<const float4*>(x + (size_t)grow * D + q * 4);
        xs[q * 4 + 0][m] = v.x; xs[q * 4 + 1][m] = v.y;
        xs[q * 4 + 2][m] = v.z; xs[q * 4 + 3][m] = v.w;
    }
    for (int idx = tid; idx < 2048; idx += 256) {
        int q = idx >> 6, n = idx & 63;
        float4 v = *reinterpret_cast<const float4*>(W + (size_t)(n0 + n) * D + q * 4);
        ws[q * 4 + 0][n] = v.x; ws[q * 4 + 1][n] = v.y;
        ws[q * 4 + 2][n] = v.z; ws[q * 4 + 3][n] = v.w;
    }
    __syncthreads();
    const int tm = (tid & 15) * 4;
    const int tn = (tid >> 4) * 4;
    float acc[4][4] = {};
#pragma unroll 4
    for (int k = 0; k < 128; ++k) {
        float4 a4 = *reinterpret_cast<const float4*>(&xs[k][tm]);
        float4 b4 = *reinterpret_cast<const float4*>(&ws[k][tn]);
        float a[4] = {a4.x, a4.y, a4.z, a4.w};
        float b[4] = {b4.x, b4.y, b4.z, b4.w};
#pragma unroll
        for (int rr = 0; rr < 4; ++rr)
#pragma unroll
            for (int cc = 0; cc < 4; ++cc) acc[rr][cc] = fmaf(a[rr], b[cc], acc[rr][cc]);
    }
#pragma unroll
    for (int rr = 0; rr < 4; ++rr) {
        int row = m0 + tm + rr;
        if (row < N) {
            float4 o = make_float4(acc[rr][0], acc[rr][1], acc[rr][2], acc[rr][3]);
            *reinterpret_cast<float4*>(h + (size_t)row * D + n0 + tn) = o;
        }
    }
}

__global__ __launch_bounds__(256) void scatter_edges(const float* __restrict__ h,
                                                     const int* __restrict__ rows,
                                                     const int* __restrict__ cols,
                                                     const float* __restrict__ vals,
                                                     float* __restrict__ out, int E) {
    int t = blockIdx.x * 256 + threadIdx.x;
    int e = t >> 5;
    if (e >= E) return;
    int q = t & 31;
    int r = rows[e];
    int c = cols[e];
    float v = vals[e];
    float4 m = reinterpret_cast<const float4*>(h + (size_t)c * D)[q];
    float* op = out + (size_t)r * D + q * 4;
    atomicAdd(op + 0, v * m.x);
    atomicAdd(op + 1, v * m.y);
    atomicAdd(op + 2, v * m.z);
    atomicAdd(op + 3, v * m.w);
}

extern "C" void kernel_launch(void* const* d_in, const int* in_sizes, int n_in,
                              void* d_out, int out_size, void* d_ws, size_t ws_size,
                              hipStream_t stream) {
    const float* x        = (const float*)d_in[0];
    const float* W        = (const float*)d_in[1];
    const int*   adj_rows = (const int*)d_in[2];
    const int*   adj_cols = (const int*)d_in[3];
    const float* adj_vals = (const float*)d_in[4];
    float* out = (float*)d_out;

    const int N = in_sizes[0] / D;
    const int E = in_sizes[2];
    const int NBUCK = (N + RPB - 1) / RPB;
    const int NT = (E + TILE - 1) / TILE;

    // ---- workspace carve (ws) ----
    size_t off = 0;
    auto carve = [&](size_t bytes) {
        void* p = (char*)d_ws + off;
        off += (bytes + 255) & ~(size_t)255;
        return p;
    };
    unsigned short* xb = (unsigned short*)carve((size_t)N * D * 2);  // 25.6 MB
    unsigned short* yb = (unsigned short*)carve((size_t)N * D * 2);  // 25.6 MB
    unsigned short* Wb = (unsigned short*)carve((size_t)D * D * 2);
    int* offsets    = (int*)carve((size_t)(N + 1) * sizeof(int));
    int* bucketCnt  = (int*)carve((size_t)BUCKMAX * sizeof(int));
    int* bucketBase = (int*)carve((size_t)(BUCKMAX + 1) * sizeof(int));
    int* bucketCur  = (int*)carve((size_t)BUCKMAX * sizeof(int));
    const size_t wsNeed = off;

    // ---- scratch carved from d_out (dead before gemm_mfma overwrites) ----
    size_t doff = 0;
    auto carveOut = [&](size_t bytes) {
        void* p = (char*)d_out + doff;
        doff += (bytes + 255) & ~(size_t)255;
        return p;
    };
    uint2* pairs_bin = (uint2*)carveOut((size_t)E * sizeof(uint2));  // 12.8 MB
    uint2* pairs_g   = (uint2*)carveOut((size_t)E * sizeof(uint2));  // 12.8 MB
    const size_t doutNeed = doff;

    const bool fits = (wsNeed <= ws_size) &&
                      (doutNeed <= (size_t)out_size * sizeof(float)) &&
                      (NBUCK <= BUCKMAX) && (N < (1 << 23));

    if (fits) {
        cast_x_hist<<<2048, 256, 0, stream>>>(x, xb, (long long)N * (D / 4),
                                              adj_rows, bucketCnt, E, NBUCK);
        scan_castW<<<2, 256, 0, stream>>>(bucketCnt, bucketBase, bucketCur,
                                          offsets, NBUCK, N, W, Wb);
        binA<<<NT, 1024, 0, stream>>>(adj_rows, adj_cols, adj_vals, bucketBase,
                                      bucketCur, pairs_bin, E, NBUCK);
        csr_build<<<NBUCK, 256, 0, stream>>>(pairs_bin, bucketBase,
                                             offsets, pairs_g, N);
        csr_gather_bf16<<<(N + 3) / 4, 256, 0, stream>>>(xb, offsets, pairs_g, yb, N);
        gemm_mfma<<<(N + 63) / 64, 256, 0, stream>>>(yb, Wb, out, N);
    } else {
        float* h = (float*)d_ws;
        hipMemsetAsync(d_out, 0, (size_t)out_size * sizeof(float), stream);
        dim3 ggrid((N + 63) / 64, D / 64);
        gemm64<<<ggrid, 256, 0, stream>>>(x, W, h, N);
        const long long tt = (long long)E * 32;
        scatter_edges<<<(int)((tt + 255) / 256), 256, 0, stream>>>(
            h, adj_rows, adj_cols, adj_vals, out, E);
    }
}

// Round 13
// 146.894 us; speedup vs baseline: 1.2168x; 1.2168x over previous
//
#include <hip/hip_runtime.h>

#define D 128          // D_IN == D_OUT == 128
#define RPB 256        // rows per bucket == rows per csr_build block
#define RPB_SHIFT 8
#define BUCKMAX 512
#define TILE 8192      // edges per binning tile
#define SEGCAP 7168    // LDS pair capacity per csr_build block (56 KiB)

typedef short bf16x8 __attribute__((ext_vector_type(8)));
typedef float f32x4 __attribute__((ext_vector_type(4)));

__device__ inline unsigned short f2bf(float f) {  // RNE float->bf16
    unsigned u = __float_as_uint(f);
    unsigned r = u + 0x7FFFu + ((u >> 16) & 1u);
    return (unsigned short)(r >> 16);
}

// ---------------------------------------------------------------------------
// fp32 -> bf16 cast of x (grid-stride); block 0 zeros bucketCnt (memset fold).
// ---------------------------------------------------------------------------
__global__ __launch_bounds__(256) void cast_x(const float* __restrict__ src,
                                              unsigned short* __restrict__ dst,
                                              long long n4,
                                              int* __restrict__ bucketCnt) {
    if (blockIdx.x == 0) {
        bucketCnt[threadIdx.x] = 0;
        bucketCnt[threadIdx.x + 256] = 0;
    }
    long long i = (long long)blockIdx.x * 256 + threadIdx.x;
    const long long stride = (long long)gridDim.x * 256;
    for (; i < n4; i += stride) {
        float4 v = reinterpret_cast<const float4*>(src)[i];
        ushort4 o;
        o.x = f2bf(v.x); o.y = f2bf(v.y); o.z = f2bf(v.z); o.w = f2bf(v.w);
        reinterpret_cast<ushort4*>(dst)[i] = o;
    }
}

// ---------------------------------------------------------------------------
// Pass 0: exact per-bucket edge counts. TILE-partitioned (196 blocks) so the
// global flush is ~50K atomics, not 800K (R12's grid-stride fusion lesson).
// ---------------------------------------------------------------------------
__global__ __launch_bounds__(1024) void bucket_hist(const int* __restrict__ rows,
                                                    int* __restrict__ bucketCnt,
                                                    int E, int NBUCK) {
    __shared__ int h[BUCKMAX];
    for (int i = threadIdx.x; i < BUCKMAX; i += 1024) h[i] = 0;
    __syncthreads();
    const int t0 = blockIdx.x * TILE;
    const int tend = min(t0 + TILE, E);
    for (int i = t0 + threadIdx.x; i < tend; i += 1024)
        atomicAdd(&h[rows[i] >> RPB_SHIFT], 1);
    __syncthreads();
    for (int i = threadIdx.x; i < NBUCK; i += 1024)
        if (h[i]) atomicAdd(&bucketCnt[i], h[i]);
}

// ---------------------------------------------------------------------------
// Block 0: exclusive scan over NBUCK (<=512) bucket counts (2/thread);
//          zero cursors. Block 1: cast W -> bf16.
// ---------------------------------------------------------------------------
__global__ __launch_bounds__(256) void scan_castW(const int* __restrict__ bucketCnt,
                                                  int* __restrict__ bucketBase,
                                                  int* __restrict__ bucketCur,
                                                  int* __restrict__ offsets,
                                                  int NBUCK, int N,
                                                  const float* __restrict__ W,
                                                  unsigned short* __restrict__ Wb) {
    const int tid = threadIdx.x;
    if (blockIdx.x == 1) {  // cast W (128x128 fp32 -> bf16)
        for (int idx = tid; idx < D * D / 4; idx += 256) {
            float4 v = reinterpret_cast<const float4*>(W)[idx];
            ushort4 o;
            o.x = f2bf(v.x); o.y = f2bf(v.y); o.z = f2bf(v.z); o.w = f2bf(v.w);
            reinterpret_cast<ushort4*>(Wb)[idx] = o;
        }
        return;
    }
    __shared__ int t[256];
    const int i0 = tid * 2, i1 = tid * 2 + 1;
    int v0 = (i0 < NBUCK) ? bucketCnt[i0] : 0;
    int v1 = (i1 < NBUCK) ? bucketCnt[i1] : 0;
    int s = v0 + v1;
    t[tid] = s;
    __syncthreads();
    for (int ofs = 1; ofs < 256; ofs <<= 1) {
        int add = (tid >= ofs) ? t[tid - ofs] : 0;
        __syncthreads();
        t[tid] += add;
        __syncthreads();
    }
    const int base0 = t[tid] - s;  // exclusive base for i0
    if (i0 < NBUCK) { bucketBase[i0] = base0;      bucketCur[i0] = 0; }
    if (i1 < NBUCK) { bucketBase[i1] = base0 + v0; bucketCur[i1] = 0; }
    if (tid == 255) {
        bucketBase[NBUCK] = t[255];
        offsets[N] = t[255];  // == E
    }
}

// ---------------------------------------------------------------------------
// Pass 1: bin edges into bucket-major PACKED pairs: (lrow8<<23 | col, val).
// Row ids kept in registers across phases (8/thread, fully unrolled).
// ---------------------------------------------------------------------------
__global__ __launch_bounds__(1024) void binA(const int* __restrict__ rows,
                                             const int* __restrict__ cols,
                                             const float* __restrict__ vals,
                                             const int* __restrict__ bucketBase,
                                             int* __restrict__ bucketCur,
                                             uint2* __restrict__ pairs_bin,
                                             int E, int NBUCK) {
    __shared__ int h[BUCKMAX];
    __shared__ int base[BUCKMAX];
    const int t0 = blockIdx.x * TILE;
    const int tend = min(t0 + TILE, E);
    for (int i = threadIdx.x; i < BUCKMAX; i += 1024) h[i] = 0;
    __syncthreads();

    int rreg[8];  // TILE/1024 == 8 edges per thread
#pragma unroll
    for (int k = 0; k < 8; ++k) {
        const int i = t0 + threadIdx.x + k * 1024;
        rreg[k] = (i < tend) ? rows[i] : -1;
        if (rreg[k] >= 0) atomicAdd(&h[rreg[k] >> RPB_SHIFT], 1);
    }
    __syncthreads();
    for (int i = threadIdx.x; i < NBUCK; i += 1024) {
        int c = h[i];
        base[i] = c ? bucketBase[i] + atomicAdd(&bucketCur[i], c) : 0;
        h[i] = 0;  // reuse as local cursor
    }
    __syncthreads();
#pragma unroll
    for (int k = 0; k < 8; ++k) {
        const int i = t0 + threadIdx.x + k * 1024;
        if (i < tend) {
            const int r = rreg[k];
            const int b = r >> RPB_SHIFT;
            const int p = base[b] + atomicAdd(&h[b], 1);
            const unsigned pk = ((unsigned)(r & (RPB - 1)) << 23) | (unsigned)cols[i];
            pairs_bin[p] = make_uint2(pk, __float_as_uint(vals[i]));
        }
    }
}

// ---------------------------------------------------------------------------
// Pass 2: ONE block per 256-row bucket (single read of its pair range).
// Sorted segment built in LDS, written out coalesced; per-row offsets
// emitted. Overflow (>SEGCAP) falls back to direct global scatter.
// ---------------------------------------------------------------------------
__global__ __launch_bounds__(256) void csr_build(const uint2* __restrict__ pairs_bin,
                                                 const int* __restrict__ bucketBase,
                                                 int* __restrict__ offsets,
                                                 uint2* __restrict__ pairs_g, int N) {
    __shared__ int hist[RPB];
    __shared__ int cur[RPB];
    __shared__ int tsum[256];
    __shared__ uint2 pr[SEGCAP];
    const int tid = threadIdx.x;
    const int buck = blockIdx.x;
    const int grow0 = buck * RPB;
    const int rbeg = bucketBase[buck], rend = bucketBase[buck + 1];

    hist[tid] = 0;
    __syncthreads();

    for (int i = rbeg + tid; i < rend; i += 256)
        atomicAdd(&hist[pairs_bin[i].x >> 23], 1);
    __syncthreads();

    int part = hist[tid];
    tsum[tid] = part;
    __syncthreads();
    for (int ofs = 1; ofs < 256; ofs <<= 1) {
        int add = (tid >= ofs) ? tsum[tid - ofs] : 0;
        __syncthreads();
        tsum[tid] += add;
        __syncthreads();
    }
    const int excl = tsum[tid] - part;
    const int segcnt = tsum[255];  // == rend - rbeg

    cur[tid] = excl;
    const int grow = grow0 + tid;
    if (grow < N) offsets[grow] = rbeg + excl;
    __syncthreads();

    if (segcnt <= SEGCAP) {
        for (int i = rbeg + tid; i < rend; i += 256) {
            uint2 e = pairs_bin[i];
            int p = atomicAdd(&cur[e.x >> 23], 1);
            pr[p] = make_uint2(e.x & 0x7FFFFFu, e.y);
        }
        __syncthreads();
        for (int p = tid; p < segcnt; p += 256) pairs_g[rbeg + p] = pr[p];
    } else {  // overflow: direct scatter (correct for any data)
        for (int i = rbeg + tid; i < rend; i += 256) {
            uint2 e = pairs_bin[i];
            int p = atomicAdd(&cur[e.x >> 23], 1);
            pairs_g[rbeg + p] = make_uint2(e.x & 0x7FFFFFu, e.y);
        }
    }
}

// ---------------------------------------------------------------------------
// Aggregation: y[row] = sum val * xb[col]  (bf16 gather, fp32 acc, bf16 out)
// One wave per row, shfl-free LDS-staged batches, 4x dwordx4 gathers in
// flight (R10-proven, 55.7 us).
// ---------------------------------------------------------------------------
__global__ __launch_bounds__(256) void csr_gather_bf16(
    const unsigned short* __restrict__ xb,
    const int* __restrict__ offsets,
    const uint2* __restrict__ pairs,
    unsigned short* __restrict__ yb, int N) {
    __shared__ uint2 prl[4][64];  // 2 KiB, wave-private slices
    const int row = blockIdx.x * 4 + (threadIdx.x >> 6);
    if (row >= N) return;
    const int wave = threadIdx.x >> 6;
    const int lane = threadIdx.x & 63;
    const int g    = lane >> 4;      // edge slot within a 4-edge group
    const int c8   = lane & 15;      // which 8-col chunk of the row
    const int beg = offsets[row], end = offsets[row + 1];

    float a[8] = {};
    for (int base = beg; base < end; base += 64) {
        const int rem = min(end - base, 64);  // wave-uniform
        uint2 e = make_uint2(0u, 0u);         // pads: col 0, val 0
        if (lane < rem) e = pairs[base + lane];
        prl[wave][lane] = e;                  // wave-private: lgkmcnt only
        __builtin_amdgcn_wave_barrier();

        for (int j0 = 0; j0 < rem; j0 += 16) {  // wave-uniform trip count
            uint2 pe[4];
            uint4 u[4];
#pragma unroll
            for (int i = 0; i < 4; ++i)
                pe[i] = prl[wave][j0 + 4 * i + g];  // 16-lane broadcast read
#pragma unroll
            for (int i = 0; i < 4; ++i)
                u[i] = *reinterpret_cast<const uint4*>(
                    xb + (size_t)pe[i].x * D + c8 * 8);
#pragma unroll
            for (int i = 0; i < 4; ++i) {
                const float v = __uint_as_float(pe[i].y);
                const unsigned w0 = u[i].x, w1 = u[i].y, w2 = u[i].z, w3 = u[i].w;
                a[0] = fmaf(v, __uint_as_float(w0 << 16), a[0]);
                a[1] = fmaf(v, __uint_as_float(w0 & 0xFFFF0000u), a[1]);
                a[2] = fmaf(v, __uint_as_float(w1 << 16), a[2]);
                a[3] = fmaf(v, __uint_as_float(w1 & 0xFFFF0000u), a[3]);
                a[4] = fmaf(v, __uint_as_float(w2 << 16), a[4]);
                a[5] = fmaf(v, __uint_as_float(w2 & 0xFFFF0000u), a[5]);
                a[6] = fmaf(v, __uint_as_float(w3 << 16), a[6]);
                a[7] = fmaf(v, __uint_as_float(w3 & 0xFFFF0000u), a[7]);
            }
        }
        __builtin_amdgcn_wave_barrier();  // don't overwrite prl while in use
    }

    // combine lane-groups: lanes l, l^16, l^32, l^48 hold same columns
#pragma unroll
    for (int i = 0; i < 8; ++i) {
        a[i] += __shfl_xor(a[i], 16);
        a[i] += __shfl_xor(a[i], 32);
    }
    if (g == 0) {
        uint4 o;
        o.x = (unsigned)f2bf(a[0]) | ((unsigned)f2bf(a[1]) << 16);
        o.y = (unsigned)f2bf(a[2]) | ((unsigned)f2bf(a[3]) << 16);
        o.z = (unsigned)f2bf(a[4]) | ((unsigned)f2bf(a[5]) << 16);
        o.w = (unsigned)f2bf(a[6]) | ((unsigned)f2bf(a[7]) << 16);
        *reinterpret_cast<uint4*>(yb + (size_t)row * D + c8 * 8) = o;
    }
}

// ---------------------------------------------------------------------------
// Projection: out = y * W^T via MFMA bf16 16x16x32 (layouts m89-verified).
// ---------------------------------------------------------------------------
__global__ __launch_bounds__(256) void gemm_mfma(const unsigned short* __restrict__ yb,
                                                 const unsigned short* __restrict__ Wb,
                                                 float* __restrict__ out, int N) {
    const int wid  = threadIdx.x >> 6;
    const int lane = threadIdx.x & 63;
    const int m0   = blockIdx.x * 64 + wid * 16;
    const int r    = lane & 15;
    const int kg   = lane >> 4;  // 0..3
    const int arow = m0 + r;

    f32x4 acc[8] = {};
#pragma unroll
    for (int ks = 0; ks < 4; ++ks) {
        const int k0 = ks * 32 + kg * 8;
        bf16x8 a = {};
        if (arow < N) a = *reinterpret_cast<const bf16x8*>(yb + (size_t)arow * D + k0);
#pragma unroll
        for (int t = 0; t < 8; ++t) {
            bf16x8 b = *reinterpret_cast<const bf16x8*>(Wb + (size_t)(t * 16 + r) * D + k0);
            acc[t] = __builtin_amdgcn_mfma_f32_16x16x32_bf16(a, b, acc[t], 0, 0, 0);
        }
    }
#pragma unroll
    for (int t = 0; t < 8; ++t) {
#pragma unroll
        for (int i = 0; i < 4; ++i) {
            const int row = m0 + kg * 4 + i;
            if (row < N) out[(size_t)row * D + t * 16 + r] = acc[t][i];
        }
    }
}

// ---------------------------------------------------------------------------
// Fallback path (tiny workspace): fp32 VALU GEMM + atomic scatter
// ---------------------------------------------------------------------------
__global__ __launch_bounds__(256) void gemm64(const float* __restrict__ x,
                                              const float* __restrict__ W,
                                              float* __restrict__ h, int N) {
    __shared__ float xs[128][64];
    __shared__ float ws[128][64];
    const int tid = threadIdx.x;
    const int m0 = blockIdx.x * 64;
    const int n0 = blockIdx.y * 64;
    for (int idx = tid; idx < 2048; idx += 256) {
        int q = idx >> 6, m = idx & 63;
        int grow = m0 + m;
        float4 v = make_float4(0.f, 0.f, 0.f, 0.f);
        if (grow < N) v = *reinterpret_cast<const float4*>(x + (size_t)grow * D + q * 4);
        xs[q * 4 + 0][m] = v.x; xs[q * 4 + 1][m] = v.y;
        xs[q * 4 + 2][m] = v.z; xs[q * 4 + 3][m] = v.w;
    }
    for (int idx = tid; idx < 2048; idx += 256) {
        int q = idx >> 6, n = idx & 63;
        float4 v = *reinterpret_cast<const float4*>(W + (size_t)(n0 + n) * D + q * 4);
        ws[q * 4 + 0][n] = v.x; ws[q * 4 + 1][n] = v.y;
        ws[q * 4 + 2][n] = v.z; ws[q * 4 + 3][n] = v.w;
    }
    __syncthreads();
    const int tm = (tid & 15) * 4;
    const int tn = (tid >> 4) * 4;
    float acc[4][4] = {};
#pragma unroll 4
    for (int k = 0; k < 128; ++k) {
        float4 a4 = *reinterpret_cast<const float4*>(&xs[k][tm]);
        float4 b4 = *reinterpret_cast<const float4*>(&ws[k][tn]);
        float a[4] = {a4.x, a4.y, a4.z, a4.w};
        float b[4] = {b4.x, b4.y, b4.z, b4.w};
#pragma unroll
        for (int rr = 0; rr < 4; ++rr)
#pragma unroll
            for (int cc = 0; cc < 4; ++cc) acc[rr][cc] = fmaf(a[rr], b[cc], acc[rr][cc]);
    }
#pragma unroll
    for (int rr = 0; rr < 4; ++rr) {
        int row = m0 + tm + rr;
        if (row < N) {
            float4 o = make_float4(acc[rr][0], acc[rr][1], acc[rr][2], acc[rr][3]);
            *reinterpret_cast<float4*>(h + (size_t)row * D + n0 + tn) = o;
        }
    }
}

__global__ __launch_bounds__(256) void scatter_edges(const float* __restrict__ h,
                                                     const int* __restrict__ rows,
                                                     const int* __restrict__ cols,
                                                     const float* __restrict__ vals,
                                                     float* __restrict__ out, int E) {
    int t = blockIdx.x * 256 + threadIdx.x;
    int e = t >> 5;
    if (e >= E) return;
    int q = t & 31;
    int r = rows[e];
    int c = cols[e];
    float v = vals[e];
    float4 m = reinterpret_cast<const float4*>(h + (size_t)c * D)[q];
    float* op = out + (size_t)r * D + q * 4;
    atomicAdd(op + 0, v * m.x);
    atomicAdd(op + 1, v * m.y);
    atomicAdd(op + 2, v * m.z);
    atomicAdd(op + 3, v * m.w);
}

extern "C" void kernel_launch(void* const* d_in, const int* in_sizes, int n_in,
                              void* d_out, int out_size, void* d_ws, size_t ws_size,
                              hipStream_t stream) {
    const float* x        = (const float*)d_in[0];
    const float* W        = (const float*)d_in[1];
    const int*   adj_rows = (const int*)d_in[2];
    const int*   adj_cols = (const int*)d_in[3];
    const float* adj_vals = (const float*)d_in[4];
    float* out = (float*)d_out;

    const int N = in_sizes[0] / D;
    const int E = in_sizes[2];
    const int NBUCK = (N + RPB - 1) / RPB;
    const int NT = (E + TILE - 1) / TILE;

    // ---- workspace carve (ws) ----
    size_t off = 0;
    auto carve = [&](size_t bytes) {
        void* p = (char*)d_ws + off;
        off += (bytes + 255) & ~(size_t)255;
        return p;
    };
    unsigned short* xb = (unsigned short*)carve((size_t)N * D * 2);  // 25.6 MB
    unsigned short* yb = (unsigned short*)carve((size_t)N * D * 2);  // 25.6 MB
    unsigned short* Wb = (unsigned short*)carve((size_t)D * D * 2);
    int* offsets    = (int*)carve((size_t)(N + 1) * sizeof(int));
    int* bucketCnt  = (int*)carve((size_t)BUCKMAX * sizeof(int));
    int* bucketBase = (int*)carve((size_t)(BUCKMAX + 1) * sizeof(int));
    int* bucketCur  = (int*)carve((size_t)BUCKMAX * sizeof(int));
    const size_t wsNeed = off;

    // ---- scratch carved from d_out (dead before gemm_mfma overwrites) ----
    size_t doff = 0;
    auto carveOut = [&](size_t bytes) {
        void* p = (char*)d_out + doff;
        doff += (bytes + 255) & ~(size_t)255;
        return p;
    };
    uint2* pairs_bin = (uint2*)carveOut((size_t)E * sizeof(uint2));  // 12.8 MB
    uint2* pairs_g   = (uint2*)carveOut((size_t)E * sizeof(uint2));  // 12.8 MB
    const size_t doutNeed = doff;

    const bool fits = (wsNeed <= ws_size) &&
                      (doutNeed <= (size_t)out_size * sizeof(float)) &&
                      (NBUCK <= BUCKMAX) && (N < (1 << 23));

    if (fits) {
        cast_x<<<2048, 256, 0, stream>>>(x, xb, (long long)N * (D / 4), bucketCnt);
        bucket_hist<<<NT, 1024, 0, stream>>>(adj_rows, bucketCnt, E, NBUCK);
        scan_castW<<<2, 256, 0, stream>>>(bucketCnt, bucketBase, bucketCur,
                                          offsets, NBUCK, N, W, Wb);
        binA<<<NT, 1024, 0, stream>>>(adj_rows, adj_cols, adj_vals, bucketBase,
                                      bucketCur, pairs_bin, E, NBUCK);
        csr_build<<<NBUCK, 256, 0, stream>>>(pairs_bin, bucketBase,
                                             offsets, pairs_g, N);
        csr_gather_bf16<<<(N + 3) / 4, 256, 0, stream>>>(xb, offsets, pairs_g, yb, N);
        gemm_mfma<<<(N + 63) / 64, 256, 0, stream>>>(yb, Wb, out, N);
    } else {
        float* h = (float*)d_ws;
        hipMemsetAsync(d_out, 0, (size_t)out_size * sizeof(float), stream);
        dim3 ggrid((N + 63) / 64, D / 64);
        gemm64<<<ggrid, 256, 0, stream>>>(x, W, h, N);
        const long long tt = (long long)E * 32;
        scatter_edges<<<(int)((tt + 255) / 256), 256, 0, stream>>>(
            h, adj_rows, adj_cols, adj_vals, out, E);
    }
}